// Round 3
// baseline (718.027 us; speedup 1.0000x reference)
//
#include <hip/hip_runtime.h>
#include <hip/hip_bf16.h>
#include <cmath>

#define N_SPH 7
#define N_RAD 6
#define NC (N_SPH * N_RAD)   // 42
#define INV_CUTOFF 0.2f

struct BesselConsts {
    float freq[NC];     // z_{l,j}, l-major
    float norm[NC];     // sqrt(2)/|j_{l+1}(z_{l,j})|
    float ycoef[N_SPH]; // sqrt((2l+1)/4pi)
};

// ---------------- host-side precompute (graph-capture time only) ----------
static double h_sph_jn(double t, int l) {
    double j0 = sin(t) / t;
    if (l == 0) return j0;
    double j1 = sin(t) / (t * t) - cos(t) / t;
    for (int i = 2; i <= l; i++) {
        double j2 = (2.0 * i - 1.0) / t * j1 - j0;
        j0 = j1; j1 = j2;
    }
    return j1;
}

static void compute_consts(BesselConsts* bc) {
    const int n = N_SPH, k = N_RAD, nz = N_RAD + N_SPH - 1;  // 12
    const double PI = 3.14159265358979323846;
    double zeros[N_SPH][12];
    for (int i = 0; i < nz; i++) zeros[0][i] = (i + 1) * PI;
    for (int l = 1; l < n; l++) {
        for (int i = 0; i < nz - l; i++) {
            double a = zeros[l - 1][i], b = zeros[l - 1][i + 1];
            double fa = h_sph_jn(a, l);
            for (int it = 0; it < 80; it++) {
                double m = 0.5 * (a + b);
                double fm = h_sph_jn(m, l);
                if (fa * fm <= 0.0) { b = m; } else { a = m; fa = fm; }
            }
            zeros[l][i] = 0.5 * (a + b);
        }
    }
    for (int l = 0; l < n; l++)
        for (int j = 0; j < k; j++) {
            bc->freq[l * k + j] = (float)zeros[l][j];
            bc->norm[l * k + j] =
                (float)(sqrt(2.0) / fabs(h_sph_jn(zeros[l][j], l + 1)));
        }
    for (int l = 0; l < n; l++)
        bc->ycoef[l] = (float)sqrt((2.0 * l + 1.0) / (4.0 * PI));
}

// ---------------- device helpers -----------------------------------------
// env(x) * NORM[c] * j_l(x * FREQ[c]); fp32 sin/cos seed, fp64 upward
// recurrence (upward recurrence amplifies seed error ~1e4x at l=6, small t;
// f64 recurrence bounds the deviation at ~0.1 absolute, threshold 1.23)
__device__ __forceinline__ float radial_val(float x, int c, int l,
                                            const BesselConsts& bc) {
    float tt = x * bc.freq[c];
    float sf = sinf(tt), cf = cosf(tt);
    double inv = 1.0 / (double)tt;
    double jl;
    double j0 = (double)sf * inv;
    if (l == 0) {
        jl = j0;
    } else {
        double j1 = ((double)sf * inv - (double)cf) * inv;
        for (int i = 2; i <= l; i++) {
            double j2 = (2.0 * i - 1.0) * inv * j1 - j0;
            j0 = j1; j1 = j2;
        }
        jl = j1;
    }
    float xp = x * x * x * x * x;  // x^5
    // p=5: env = 1/x + x^5*(-21 + x*(35 - 15x))
    float env = 1.0f / x + xp * (-21.0f + x * (35.0f - 15.0f * x));
    return env * bc.norm[c] * (float)jl;
}

__device__ __forceinline__ float legendre_pl(float cth, int l) {
    if (l == 0) return 1.0f;
    float p0 = 1.0f, p1 = cth;
    for (int i = 2; i <= l; i++) {
        float p2 = ((2 * i - 1) * cth * p1 - (i - 1) * p0) / (float)i;
        p0 = p1; p1 = p2;
    }
    return p1;
}

// ---------------- kernel A: rbf table [E,42] fp32 -------------------------
__global__ __launch_bounds__(256) void rbf_kernel(
    const float* __restrict__ dist, float* __restrict__ rbf, int ntot,
    BesselConsts bc) {
    int tid = blockIdx.x * 256 + threadIdx.x;
    if (tid >= ntot) return;
    int e = tid / NC;
    int c = tid - e * NC;
    int l = c / N_RAD;
    float x = dist[e] * INV_CUTOFF;
    rbf[tid] = radial_val(x, c, l, bc);
}

// ---------------- kernel B: gather + angular, f32 output ------------------
__global__ __launch_bounds__(256) void out_kernel(
    const float* __restrict__ angle, const int* __restrict__ idx,
    const float* __restrict__ rbf, float* __restrict__ out, int ntot,
    BesselConsts bc) {
    int tid = blockIdx.x * 256 + threadIdx.x;
    if (tid >= ntot) return;
    int t = tid / NC;
    int c = tid - t * NC;
    int l = c / N_RAD;
    float cth = cosf(angle[t]);
    float pl = legendre_pl(cth, l);
    float r = rbf[idx[t] * NC + c];
    out[tid] = bc.ycoef[l] * pl * r;
}

// ---------------- fallback: fused, no workspace ---------------------------
__global__ __launch_bounds__(256) void fused_kernel(
    const float* __restrict__ dist, const float* __restrict__ angle,
    const int* __restrict__ idx, float* __restrict__ out, int ntot,
    BesselConsts bc) {
    int tid = blockIdx.x * 256 + threadIdx.x;
    if (tid >= ntot) return;
    int t = tid / NC;
    int c = tid - t * NC;
    int l = c / N_RAD;
    int e = idx[t];
    float x = dist[e] * INV_CUTOFF;
    float r = radial_val(x, c, l, bc);
    float cth = cosf(angle[t]);
    float pl = legendre_pl(cth, l);
    out[tid] = bc.ycoef[l] * pl * r;
}

extern "C" void kernel_launch(void* const* d_in, const int* in_sizes, int n_in,
                              void* d_out, int out_size, void* d_ws,
                              size_t ws_size, hipStream_t stream) {
    const float* dist = (const float*)d_in[0];
    const float* angle = (const float*)d_in[1];
    const int* idx = (const int*)d_in[2];
    float* out = (float*)d_out;

    int E_ = in_sizes[0];
    int T_ = in_sizes[1];
    int na = E_ * NC;
    int nb = T_ * NC;

    BesselConsts bc;
    compute_consts(&bc);

    if (ws_size >= (size_t)na * sizeof(float)) {
        float* rbf = (float*)d_ws;
        rbf_kernel<<<(na + 255) / 256, 256, 0, stream>>>(dist, rbf, na, bc);
        out_kernel<<<(nb + 255) / 256, 256, 0, stream>>>(angle, idx, rbf, out,
                                                         nb, bc);
    } else {
        fused_kernel<<<(nb + 255) / 256, 256, 0, stream>>>(dist, angle, idx,
                                                           out, nb, bc);
    }
}

// Round 4
// 475.107 us; speedup vs baseline: 1.5113x; 1.5113x over previous
//
#include <hip/hip_runtime.h>
#include <hip/hip_bf16.h>
#include <cmath>

#define N_SPH 7
#define N_RAD 6
#define NC (N_SPH * N_RAD)   // 42
#define INV_CUTOFF 0.2f

struct BesselConsts {
    float freq[NC];     // z_{l,j}, l-major
    float norm[NC];     // sqrt(2)/|j_{l+1}(z_{l,j})|
    float ycoef[N_SPH]; // sqrt((2l+1)/4pi)
};

// ---------------- host-side precompute (graph-capture time only) ----------
static double h_sph_jn(double t, int l) {
    double j0 = sin(t) / t;
    if (l == 0) return j0;
    double j1 = sin(t) / (t * t) - cos(t) / t;
    for (int i = 2; i <= l; i++) {
        double j2 = (2.0 * i - 1.0) / t * j1 - j0;
        j0 = j1; j1 = j2;
    }
    return j1;
}

static void compute_consts(BesselConsts* bc) {
    const int n = N_SPH, k = N_RAD, nz = N_RAD + N_SPH - 1;  // 12
    const double PI = 3.14159265358979323846;
    double zeros[N_SPH][12];
    for (int i = 0; i < nz; i++) zeros[0][i] = (i + 1) * PI;
    for (int l = 1; l < n; l++) {
        for (int i = 0; i < nz - l; i++) {
            double a = zeros[l - 1][i], b = zeros[l - 1][i + 1];
            double fa = h_sph_jn(a, l);
            for (int it = 0; it < 80; it++) {
                double m = 0.5 * (a + b);
                double fm = h_sph_jn(m, l);
                if (fa * fm <= 0.0) { b = m; } else { a = m; fa = fm; }
            }
            zeros[l][i] = 0.5 * (a + b);
        }
    }
    for (int l = 0; l < n; l++)
        for (int j = 0; j < k; j++) {
            bc->freq[l * k + j] = (float)zeros[l][j];
            bc->norm[l * k + j] =
                (float)(sqrt(2.0) / fabs(h_sph_jn(zeros[l][j], l + 1)));
        }
    for (int l = 0; l < n; l++)
        bc->ycoef[l] = (float)sqrt((2.0 * l + 1.0) / (4.0 * PI));
}

// ---------------- kernel A: per-edge radial table [E,42] fp32 -------------
// Fully unrolled (l,j): all BesselConsts indices compile-time -> kernarg
// s_loads, no scratch. f32 sincos seed + f64 Newton-refined 1/t + f64 upward
// recurrence (seed error amplified ~1e4x at l=6, t~1 -> keeps absmax ~0.25).
__global__ __launch_bounds__(256) void rbf_kernel(
    const float* __restrict__ dist, float* __restrict__ rbf, int E_,
    BesselConsts bc) {
    __shared__ float stage[256 * (NC + 1)];  // stride 43: odd -> no 4-way conflict
    const int tix = threadIdx.x;
    const int e0 = blockIdx.x * 256;
    const int e = e0 + tix;
    const bool valid = e < E_;
    float x = valid ? dist[e] * INV_CUTOFF : 0.5f;
    float xp = x * x * x * x * x;  // x^5
    // p=5 envelope: 1/x + x^5*(-21 + x*(35 - 15x))
    float env = 1.0f / x + xp * (-21.0f + x * (35.0f - 15.0f * x));

#pragma unroll
    for (int l = 0; l < N_SPH; ++l) {
#pragma unroll
        for (int j = 0; j < N_RAD; ++j) {
            const int c = l * N_RAD + j;
            float tt = x * bc.freq[c];
            float s, co;
            sincosf(tt, &s, &co);
            float rf = 1.0f / tt;                 // f32 IEEE div (cheap seq)
            double r = (double)rf;
            r = r * (2.0 - (double)tt * r);       // Newton: ~1e-15 rel
            double jv;
            double j0 = (double)s * r;
            if (l == 0) {
                jv = j0;
            } else {
                double j1 = ((double)s * r - (double)co) * r;
#pragma unroll
                for (int i = 2; i <= l; ++i) {
                    double j2 = (2.0 * i - 1.0) * r * j1 - j0;
                    j0 = j1; j1 = j2;
                }
                jv = j1;
            }
            stage[tix * (NC + 1) + c] = env * bc.norm[c] * (float)jv;
        }
    }
    __syncthreads();
    // coalesced copy-out
    const int rows = min(256, E_ - e0);
    const int nelem = rows * NC;
    const size_t base = (size_t)e0 * NC;
#pragma unroll
    for (int it = 0; it < NC; ++it) {
        int i = it * 256 + tix;
        if (i < nelem) {
            unsigned rrow = (unsigned)i / (unsigned)NC;  // magic mul
            unsigned ccol = (unsigned)i - rrow * NC;
            rbf[base + i] = stage[rrow * (NC + 1) + ccol];
        }
    }
}

// ---------------- kernel B: per-row angular + gather ----------------------
// Phase 1: each thread computes cos + all 7 ycoef*P_l once (unrolled ->
// reciprocal multiplies) into LDS. Phase 2: 42 coalesced sweeps, each elem
// = 2 LDS reads + 1 gather + 1 fmul + 1 coalesced store.
__global__ __launch_bounds__(256) void out_kernel(
    const float* __restrict__ angle, const int* __restrict__ idx,
    const float* __restrict__ rbf, float* __restrict__ out, int T_,
    BesselConsts bc) {
    __shared__ float yP[256 * 8];  // stride 8
    __shared__ int sidx[256];
    const int tix = threadIdx.x;
    const int t0 = blockIdx.x * 256;
    const int t = t0 + tix;

    float cth = 0.0f;
    int id = 0;
    if (t < T_) {
        cth = cosf(angle[t]);
        id = idx[t];
    }
    float P[N_SPH];
    P[0] = 1.0f;
    P[1] = cth;
#pragma unroll
    for (int l = 2; l < N_SPH; ++l)
        P[l] = ((2 * l - 1) * cth * P[l - 1] - (l - 1) * P[l - 2]) *
               (1.0f / (float)l);
#pragma unroll
    for (int l = 0; l < N_SPH; ++l) yP[tix * 8 + l] = bc.ycoef[l] * P[l];
    sidx[tix] = id;
    __syncthreads();

    const int rows = min(256, T_ - t0);
    const int nelem = rows * NC;
    const size_t base = (size_t)t0 * NC;
#pragma unroll
    for (int it = 0; it < NC; ++it) {
        int ei = it * 256 + tix;
        if (ei < nelem) {
            unsigned row = (unsigned)ei / (unsigned)NC;   // magic mul
            unsigned col = (unsigned)ei - row * NC;
            unsigned l = col / (unsigned)N_RAD;           // magic mul
            float r = rbf[(size_t)sidx[row] * NC + col];
            out[base + ei] = yP[row * 8 + l] * r;
        }
    }
}

// ---------------- fallback: fused, no workspace (correctness path) --------
__global__ __launch_bounds__(256) void fused_kernel(
    const float* __restrict__ dist, const float* __restrict__ angle,
    const int* __restrict__ idx, float* __restrict__ out, int ntot,
    BesselConsts bc) {
    int tid = blockIdx.x * 256 + threadIdx.x;
    if (tid >= ntot) return;
    int t = tid / NC;
    int c = tid - t * NC;
    int l = c / N_RAD;
    int e = idx[t];
    float x = dist[e] * INV_CUTOFF;
    float tt = x * bc.freq[c];
    float s, co;
    sincosf(tt, &s, &co);
    double r = 1.0 / (double)tt;
    double j0 = (double)s * r, jv;
    if (l == 0) jv = j0;
    else {
        double j1 = ((double)s * r - (double)co) * r;
        for (int i = 2; i <= l; ++i) {
            double j2 = (2.0 * i - 1.0) * r * j1 - j0;
            j0 = j1; j1 = j2;
        }
        jv = j1;
    }
    float xp = x * x * x * x * x;
    float env = 1.0f / x + xp * (-21.0f + x * (35.0f - 15.0f * x));
    float p0 = 1.0f, p1 = cosf(angle[t]), pl = (l == 0) ? 1.0f : p1;
    for (int i = 2; i <= l; ++i) {
        float p2 = ((2 * i - 1) * p1 * cosf(angle[t]) - (i - 1) * p0) / i;
        p0 = p1; p1 = p2; pl = p2;
    }
    out[tid] = bc.ycoef[l] * pl * env * bc.norm[c] * (float)jv;
}

extern "C" void kernel_launch(void* const* d_in, const int* in_sizes, int n_in,
                              void* d_out, int out_size, void* d_ws,
                              size_t ws_size, hipStream_t stream) {
    const float* dist = (const float*)d_in[0];
    const float* angle = (const float*)d_in[1];
    const int* idx = (const int*)d_in[2];
    float* out = (float*)d_out;

    int E_ = in_sizes[0];
    int T_ = in_sizes[1];
    int na = E_ * NC;
    int nb = T_ * NC;

    BesselConsts bc;
    compute_consts(&bc);

    if (ws_size >= (size_t)na * sizeof(float)) {
        float* rbf = (float*)d_ws;
        rbf_kernel<<<(E_ + 255) / 256, 256, 0, stream>>>(dist, rbf, E_, bc);
        out_kernel<<<(T_ + 255) / 256, 256, 0, stream>>>(angle, idx, rbf, out,
                                                         T_, bc);
    } else {
        fused_kernel<<<(nb + 255) / 256, 256, 0, stream>>>(dist, angle, idx,
                                                           out, nb, bc);
    }
}